// Round 1
// baseline (2487.930 us; speedup 1.0000x reference)
//
#include <hip/hip_runtime.h>

#define NODES 40000
#define EDGES 640000

__device__ __forceinline__ float silu_f(float x) { return x / (1.0f + __expf(-x)); }

// ---------------------------------------------------------------------------
// Real-basis Clebsch-Gordan contraction, constants derived from the reference
// _real_cg (U-transform of complex CG, real/imag selection). Index orders:
// v: [y,z,x] ; t: [xy,yz,z2,xz,x2y2]  (m = -l..l). Validated by unitarity
// norms + rotation-generator structure + Gaunt sign checks.
// ---------------------------------------------------------------------------
__device__ __forceinline__ void tp_uuu(const float* wv,
                                       float as, const float* av, const float* at,
                                       float bs, const float* bv, const float* bt,
                                       float& ms, float* mv, float* mt)
{
    const float CR = 0.70710678f;   // 1/sqrt(2)
    const float K1 = 0.31622777f;   // 1/sqrt(10)
    const float K3 = 0.54772256f;   // sqrt(3)/sqrt(10)
    const float KA = 0.40824829f;   // 1/sqrt(6)
    const float KB = 0.70710678f;   // 1/sqrt(2)
    const float KC = 0.81649658f;   // sqrt(6)/3
    const float L4 = 0.63245553f;   // 2/sqrt(10)
    const float G2 = 0.53452248f;   // 2/sqrt(14)
    const float G1 = 0.26726124f;   // 1/sqrt(14)
    const float HH = 0.46291005f;   // sqrt(3/14)

    float os = 0.f;
    float ov0 = 0.f, ov1 = 0.f, ov2 = 0.f;
    float ot0 = 0.f, ot1 = 0.f, ot2 = 0.f, ot3 = 0.f, ot4 = 0.f;

    // p0 (0,0,0)
    os += wv[0] * as * bs;
    // p1 (0,1,1)
    ov0 += wv[1] * as * bv[0]; ov1 += wv[1] * as * bv[1]; ov2 += wv[1] * as * bv[2];
    // p2 (0,2,2)
    ot0 += wv[2] * as * bt[0]; ot1 += wv[2] * as * bt[1]; ot2 += wv[2] * as * bt[2];
    ot3 += wv[2] * as * bt[3]; ot4 += wv[2] * as * bt[4];
    // p3 (1,0,1)
    ov0 += wv[3] * av[0] * bs; ov1 += wv[3] * av[1] * bs; ov2 += wv[3] * av[2] * bs;
    // p4 (1,1,0): -1/sqrt(3) * dot
    os += wv[4] * (-0.57735027f) * (av[0]*bv[0] + av[1]*bv[1] + av[2]*bv[2]);
    // p5 (1,1,1): cross (cyclic in [y,z,x]) * 1/sqrt(2)
    ov0 += wv[5] * CR * (av[1]*bv[2] - av[2]*bv[1]);
    ov1 += wv[5] * CR * (av[2]*bv[0] - av[0]*bv[2]);
    ov2 += wv[5] * CR * (av[0]*bv[1] - av[1]*bv[0]);
    // p6 (1,1,2): symmetric traceless
    ot0 += wv[6] * CR * (av[2]*bv[0] + av[0]*bv[2]);
    ot1 += wv[6] * CR * (av[0]*bv[1] + av[1]*bv[0]);
    ot2 += wv[6] * 0.40824829f * (2.f*av[1]*bv[1] - av[2]*bv[2] - av[0]*bv[0]);
    ot3 += wv[6] * CR * (av[2]*bv[1] + av[1]*bv[2]);
    ot4 += wv[6] * CR * (av[2]*bv[2] - av[0]*bv[0]);
    // p7 (1,2,1)
    ov0 += wv[7] * (-K3*av[1]*bt[1] + K1*av[0]*bt[2] - K3*av[2]*bt[0] + K3*av[0]*bt[4]);
    ov1 += wv[7] * (-2.f*K1*av[1]*bt[2] - K3*av[2]*bt[3] - K3*av[0]*bt[1]);
    ov2 += wv[7] * (-K3*av[1]*bt[3] + K1*av[2]*bt[2] - K3*av[0]*bt[0] - K3*av[2]*bt[4]);
    // p8 (1,2,2)
    ot0 += wv[8] * ( KC*av[1]*bt[4] - KA*av[2]*bt[3] + KA*av[0]*bt[1]);
    ot1 += wv[8] * ( KA*av[1]*bt[3] - KB*av[2]*bt[2] - KA*av[0]*bt[0] - KA*av[2]*bt[4]);
    ot2 += wv[8] * ( KB*av[2]*bt[1] - KB*av[0]*bt[3]);
    ot3 += wv[8] * (-KA*av[1]*bt[1] + KB*av[0]*bt[2] + KA*av[2]*bt[0] - KA*av[0]*bt[4]);
    ot4 += wv[8] * (-KC*av[1]*bt[0] + KA*av[2]*bt[1] + KA*av[0]*bt[3]);
    // p9 (2,0,2)
    ot0 += wv[9] * at[0] * bs; ot1 += wv[9] * at[1] * bs; ot2 += wv[9] * at[2] * bs;
    ot3 += wv[9] * at[3] * bs; ot4 += wv[9] * at[4] * bs;
    // p10 (2,1,1): (1,2,1) with first two slots swapped
    ov0 += wv[10] * (-K3*bv[1]*at[1] + K1*bv[0]*at[2] - K3*bv[2]*at[0] + K3*bv[0]*at[4]);
    ov1 += wv[10] * (-2.f*K1*bv[1]*at[2] - K3*bv[2]*at[3] - K3*bv[0]*at[1]);
    ov2 += wv[10] * (-K3*bv[1]*at[3] + K1*bv[2]*at[2] - K3*bv[0]*at[0] - K3*bv[2]*at[4]);
    // p11 (2,1,2): = -(1,2,2) with swapped roles
    ot0 -= wv[11] * ( KC*bv[1]*at[4] - KA*bv[2]*at[3] + KA*bv[0]*at[1]);
    ot1 -= wv[11] * ( KA*bv[1]*at[3] - KB*bv[2]*at[2] - KA*bv[0]*at[0] - KA*bv[2]*at[4]);
    ot2 -= wv[11] * ( KB*bv[2]*at[1] - KB*bv[0]*at[3]);
    ot3 -= wv[11] * (-KA*bv[1]*at[1] + KB*bv[0]*at[2] + KA*bv[2]*at[0] - KA*bv[0]*at[4]);
    ot4 -= wv[11] * (-KC*bv[1]*at[0] + KA*bv[2]*at[1] + KA*bv[0]*at[3]);
    // p12 (2,2,0): +1/sqrt(5) * dot
    os += wv[12] * 0.44721360f * (at[0]*bt[0] + at[1]*bt[1] + at[2]*bt[2] + at[3]*bt[3] + at[4]*bt[4]);
    // p13 (2,2,1): antisymmetric
    ov0 += wv[13] * ( K1*(at[0]*bt[1] - at[1]*bt[0]) + K3*(at[3]*bt[2] - at[2]*bt[3]) + K1*(at[4]*bt[3] - at[3]*bt[4]) );
    ov1 += wv[13] * ( L4*(at[0]*bt[4] - at[4]*bt[0]) + K1*(at[1]*bt[3] - at[3]*bt[1]) );
    ov2 += wv[13] * ( K1*(at[3]*bt[0] - at[0]*bt[3]) + K3*(at[2]*bt[1] - at[1]*bt[2]) + K1*(at[4]*bt[1] - at[1]*bt[4]) );
    // p14 (2,2,2): symmetric
    ot0 += wv[14] * ( G2*(at[2]*bt[0] + at[0]*bt[2]) - HH*(at[1]*bt[3] + at[3]*bt[1]) );
    ot1 += wv[14] * (-HH*(at[3]*bt[0] + at[0]*bt[3]) + HH*(at[1]*bt[4] + at[4]*bt[1]) - G1*(at[2]*bt[1] + at[1]*bt[2]) );
    ot2 += wv[14] * ( G2*(at[0]*bt[0] + at[4]*bt[4] - at[2]*bt[2]) - G1*(at[1]*bt[1] + at[3]*bt[3]) );
    ot3 += wv[14] * (-HH*(at[1]*bt[0] + at[0]*bt[1]) - HH*(at[3]*bt[4] + at[4]*bt[3]) - G1*(at[2]*bt[3] + at[3]*bt[2]) );
    ot4 += wv[14] * ( G2*(at[2]*bt[4] + at[4]*bt[2]) + HH*(at[1]*bt[1] - at[3]*bt[3]) );

    // NIN normalization: {0:3, 1:6, 2:6}
    ms = os * 0.57735027f;
    mv[0] = ov0 * 0.40824829f; mv[1] = ov1 * 0.40824829f; mv[2] = ov2 * 0.40824829f;
    mt[0] = ot0 * 0.40824829f; mt[1] = ot1 * 0.40824829f; mt[2] = ot2 * 0.40824829f;
    mt[3] = ot3 * 0.40824829f; mt[4] = ot4 * 0.40824829f;
}

// ---------------------------------------------------------------------------
// Shared radial-MLP block phases. Block = 256 threads = 32 edges x 8 channels.
// ---------------------------------------------------------------------------
template <int OD>
__device__ __forceinline__ void radial_block(
    const float* __restrict__ ev, const float* __restrict__ w1,
    const float* __restrict__ b1, const float* __restrict__ w2,
    const float* __restrict__ b2,
    float* emb_s /*32*16*/, float* hid_s /*32*68*/, float* w2t /*OD*68*/,
    int e0, int tid, float* wv /*[OD/8] outputs for this (e,c)*/)
{
    // stage w2^T into LDS (row o, padded stride 68)
    for (int idx = tid; idx < 64 * OD; idx += 256) {
        int j = idx / OD, o = idx - j * OD;
        w2t[o * 68 + j] = w2[idx];
    }
    // soft one-hot (compact support: |d|<1)
    for (int idx = tid; idx < 512; idx += 256) {
        int e = idx >> 4, i = idx & 15;
        int eg = e0 + e;
        float ex = ev[eg * 3 + 0], ey = ev[eg * 3 + 1], ez = ev[eg * 3 + 2];
        float r = sqrtf(ex * ex + ey * ey + ez * ez + 1e-12f);
        float d = r * (17.0f / 3.0f) - (float)(i + 1);
        float f = 0.0f;
        if (fabsf(d) < 1.0f) f = 8.433572869f * __expf(-2.0f / (1.0f - d * d));
        emb_s[idx] = f;
    }
    __syncthreads();
    // hidden = silu(emb @ w1 + b1): each thread computes 8 of 64 entries
    {
        int e = tid >> 3, jb = (tid & 7) * 8;
        float acc[8];
        #pragma unroll
        for (int q = 0; q < 8; ++q) acc[q] = b1[jb + q];
        #pragma unroll
        for (int i = 0; i < 16; ++i) {
            float evv = emb_s[e * 16 + i];
            float4 wa = *(const float4*)&w1[i * 64 + jb];
            float4 wb = *(const float4*)&w1[i * 64 + jb + 4];
            acc[0] += evv * wa.x; acc[1] += evv * wa.y; acc[2] += evv * wa.z; acc[3] += evv * wa.w;
            acc[4] += evv * wb.x; acc[5] += evv * wb.y; acc[6] += evv * wb.z; acc[7] += evv * wb.w;
        }
        #pragma unroll
        for (int q = 0; q < 8; ++q) hid_s[e * 68 + jb + q] = silu_f(acc[q]);
    }
    __syncthreads();
    // w[p] = hidden . w2[:, p*8+c] + b2  for this thread's (e,c)
    {
        const int NP = OD / 8;
        int e = tid >> 3, c = tid & 7;
        #pragma unroll
        for (int p = 0; p < NP; ++p) wv[p] = b2[p * 8 + c];
        for (int jb = 0; jb < 64; jb += 4) {
            float4 h4 = *(const float4*)&hid_s[e * 68 + jb];
            #pragma unroll
            for (int p = 0; p < NP; ++p) {
                float4 w4 = *(const float4*)&w2t[(p * 8 + c) * 68 + jb];
                wv[p] += h4.x * w4.x + h4.y * w4.y + h4.z * w4.z + h4.w * w4.w;
            }
        }
    }
}

// ---------------------------------------------------------------------------
// Layer 0: radial(od=24) + tp_first + atomic scatter + hb = act(m)
// ---------------------------------------------------------------------------
__launch_bounds__(256, 2)
__global__ void layer0_edge(const int* __restrict__ eidx, const float* __restrict__ ev,
                            const int* __restrict__ xs, const float* __restrict__ embw,
                            const float* __restrict__ w1, const float* __restrict__ b1,
                            const float* __restrict__ w2, const float* __restrict__ b2,
                            float* __restrict__ agg, float* __restrict__ hb)
{
    __shared__ float w2t[24 * 68];
    __shared__ float hid_s[32 * 68];
    __shared__ float emb_s[32 * 16];
    const int tid = threadIdx.x;
    const int e0 = blockIdx.x * 32;

    float wv[3];
    radial_block<24>(ev, w1, b1, w2, b2, emb_s, hid_s, w2t, e0, tid, wv);

    const int e = tid >> 3, c = tid & 7;
    const int eg = e0 + e;
    const int sn = eidx[eg];
    const int dn = eidx[EDGES + eg];
    float hs = embw[xs[sn] * 8 + c];

    float ex = ev[eg * 3 + 0], ey = ev[eg * 3 + 1], ez = ev[eg * 3 + 2];
    float r = sqrtf(ex * ex + ey * ey + ez * ez + 1e-12f);
    float inv = 1.0f / r;
    float x = ex * inv, y = ey * inv, z = ez * inv;
    const float c3 = 1.7320508f, c15 = 3.8729833f, c5 = 2.2360680f;
    float sh1 = c3 * y, sh2 = c3 * z, sh3 = c3 * x;
    float sh4 = c15 * x * y, sh5 = c15 * y * z, sh6 = 0.5f * c5 * (3.f * z * z - 1.f);
    float sh7 = c15 * x * z, sh8 = 0.5f * c15 * (x * x - y * y);

    float ms = wv[0] * hs;
    float mv0 = wv[1] * hs * sh1, mv1 = wv[1] * hs * sh2, mv2 = wv[1] * hs * sh3;
    float mt0 = wv[2] * hs * sh4, mt1 = wv[2] * hs * sh5, mt2 = wv[2] * hs * sh6;
    float mt3 = wv[2] * hs * sh7, mt4 = wv[2] * hs * sh8;

    float* ag = agg + dn * 72;
    atomicAdd(&ag[c], ms);
    atomicAdd(&ag[8 + c * 3 + 0], mv0); atomicAdd(&ag[8 + c * 3 + 1], mv1); atomicAdd(&ag[8 + c * 3 + 2], mv2);
    atomicAdd(&ag[32 + c * 5 + 0], mt0); atomicAdd(&ag[32 + c * 5 + 1], mt1); atomicAdd(&ag[32 + c * 5 + 2], mt2);
    atomicAdd(&ag[32 + c * 5 + 3], mt3); atomicAdd(&ag[32 + c * 5 + 4], mt4);

    float* hbe = hb + eg * 72;
    hbe[c] = silu_f(ms);
    hbe[8 + c * 3 + 0] = mv0; hbe[8 + c * 3 + 1] = mv1; hbe[8 + c * 3 + 2] = mv2;
    hbe[32 + c * 5 + 0] = mt0; hbe[32 + c * 5 + 1] = mt1; hbe[32 + c * 5 + 2] = mt2;
    hbe[32 + c * 5 + 3] = mt3; hbe[32 + c * 5 + 4] = mt4;
}

// ---------------------------------------------------------------------------
// Layers 1/2: radial(od=120) + tp_uuu(h[src], hb) + atomic scatter + hb=act(m)
// ---------------------------------------------------------------------------
__launch_bounds__(256, 2)
__global__ void tp_edge(const int* __restrict__ eidx, const float* __restrict__ ev,
                        const float* __restrict__ h,
                        const float* __restrict__ w1, const float* __restrict__ b1,
                        const float* __restrict__ w2, const float* __restrict__ b2,
                        float* __restrict__ hb, float* __restrict__ agg)
{
    __shared__ float w2t[120 * 68];
    __shared__ float hid_s[32 * 68];
    __shared__ float emb_s[32 * 16];
    const int tid = threadIdx.x;
    const int e0 = blockIdx.x * 32;

    float wv[15];
    radial_block<120>(ev, w1, b1, w2, b2, emb_s, hid_s, w2t, e0, tid, wv);

    const int e = tid >> 3, c = tid & 7;
    const int eg = e0 + e;
    const int sn = eidx[eg];
    const int dn = eidx[EDGES + eg];

    const float* hn = h + sn * 72;
    float as = hn[c];
    float av[3], at[5], bv[3], bt[5];
    #pragma unroll
    for (int i = 0; i < 3; ++i) av[i] = hn[8 + c * 3 + i];
    #pragma unroll
    for (int i = 0; i < 5; ++i) at[i] = hn[32 + c * 5 + i];
    float* hbe = hb + eg * 72;
    float bs = hbe[c];
    #pragma unroll
    for (int i = 0; i < 3; ++i) bv[i] = hbe[8 + c * 3 + i];
    #pragma unroll
    for (int i = 0; i < 5; ++i) bt[i] = hbe[32 + c * 5 + i];

    float ms, mv[3], mt[5];
    tp_uuu(wv, as, av, at, bs, bv, bt, ms, mv, mt);

    float* ag = agg + dn * 72;
    atomicAdd(&ag[c], ms);
    #pragma unroll
    for (int i = 0; i < 3; ++i) atomicAdd(&ag[8 + c * 3 + i], mv[i]);
    #pragma unroll
    for (int i = 0; i < 5; ++i) atomicAdd(&ag[32 + c * 5 + i], mt[i]);

    hbe[c] = silu_f(ms);
    #pragma unroll
    for (int i = 0; i < 3; ++i) hbe[8 + c * 3 + i] = mv[i];
    #pragma unroll
    for (int i = 0; i < 5; ++i) hbe[32 + c * 5 + i] = mt[i];
}

// ---------------------------------------------------------------------------
// Node updates
// ---------------------------------------------------------------------------
__global__ void node0(const int* __restrict__ xs, const float* __restrict__ embw,
                      const float* __restrict__ lin0, const float* __restrict__ agg,
                      float* __restrict__ h)
{
    int idx = blockIdx.x * 256 + threadIdx.x;   // n*8 + c
    int n = idx >> 3, c = idx & 7;
    int xb = xs[n] * 8;
    float dot = 0.f;
    #pragma unroll
    for (int d = 0; d < 8; ++d) dot += embw[xb + d] * lin0[d * 8 + c];
    const float* an = agg + n * 72;
    float* hn = h + n * 72;
    hn[c] = silu_f(an[c] * 0.25f + dot * 0.35355339f);
    #pragma unroll
    for (int i = 0; i < 3; ++i) hn[8 + c * 3 + i] = an[8 + c * 3 + i] * 0.25f;
    #pragma unroll
    for (int i = 0; i < 5; ++i) hn[32 + c * 5 + i] = an[32 + c * 5 + i] * 0.25f;
}

__global__ void node12(const float* __restrict__ hin, const float* __restrict__ lin,
                       const float* __restrict__ agg, float* __restrict__ hout)
{
    int idx = blockIdx.x * 256 + threadIdx.x;   // n*8 + d
    int n = idx >> 3, d = idx & 7;
    const float* hn = hin + n * 72;
    const float* an = agg + n * 72;
    float* ho = hout + n * 72;
    float s = 0.f;
    #pragma unroll
    for (int c = 0; c < 8; ++c) s += hn[c] * lin[c * 8 + d];
    ho[d] = silu_f(s * 0.35355339f + an[d] * 0.25f);
    #pragma unroll
    for (int i = 0; i < 3; ++i) {
        float v = 0.f;
        #pragma unroll
        for (int c = 0; c < 8; ++c) v += hn[8 + c * 3 + i] * lin[64 + c * 8 + d];
        ho[8 + d * 3 + i] = v * 0.35355339f + an[8 + d * 3 + i] * 0.25f;
    }
    #pragma unroll
    for (int i = 0; i < 5; ++i) {
        float t = 0.f;
        #pragma unroll
        for (int c = 0; c < 8; ++c) t += hn[32 + c * 5 + i] * lin[128 + c * 8 + d];
        ho[32 + d * 5 + i] = t * 0.35355339f + an[32 + d * 5 + i] * 0.25f;
    }
}

__global__ void out_kernel(const float* __restrict__ h, const float* __restrict__ outw,
                           float* __restrict__ out)
{
    int idx = blockIdx.x * 256 + threadIdx.x;   // n*8 + k
    int n = idx >> 3, k = idx & 7;
    const float* hn = h + n * 72;
    float s[8], v[24], t[40];
    #pragma unroll
    for (int i = 0; i < 8; ++i) s[i] = hn[i];
    #pragma unroll
    for (int i = 0; i < 24; ++i) v[i] = hn[8 + i];
    #pragma unroll
    for (int i = 0; i < 40; ++i) t[i] = hn[32 + i];
    float acc = 0.f;
    #pragma unroll
    for (int i = 0; i < 8; ++i) {
        #pragma unroll
        for (int j = 0; j < 8; ++j) {
            float dv = v[i*3+0]*v[j*3+0] + v[i*3+1]*v[j*3+1] + v[i*3+2]*v[j*3+2];
            float dt = t[i*5+0]*t[j*5+0] + t[i*5+1]*t[j*5+1] + t[i*5+2]*t[j*5+2]
                     + t[i*5+3]*t[j*5+3] + t[i*5+4]*t[j*5+4];
            int o = (i * 8 + j) * 8 + k;
            acc += s[i] * s[j] * outw[o]
                 + dv * 0.57735027f * outw[512 + o]
                 + dt * 0.44721360f * outw[1024 + o];
        }
    }
    out[n * 8 + k] = acc * 0.072168784f;   // 1/sqrt(3*8*8)
}

// ---------------------------------------------------------------------------
extern "C" void kernel_launch(void* const* d_in, const int* in_sizes, int n_in,
                              void* d_out, int out_size, void* d_ws, size_t ws_size,
                              hipStream_t stream)
{
    const int*   x    = (const int*)  d_in[0];
    const int*   eidx = (const int*)  d_in[1];
    const float* ev   = (const float*)d_in[2];
    const float* embw = (const float*)d_in[3];
    const float* lin0 = (const float*)d_in[4];
    const float* lin1 = (const float*)d_in[5];
    const float* lin2 = (const float*)d_in[6];
    const float* outw = (const float*)d_in[7];
    const float* r0w1 = (const float*)d_in[8];
    const float* r0b1 = (const float*)d_in[9];
    const float* r0w2 = (const float*)d_in[10];
    const float* r0b2 = (const float*)d_in[11];
    const float* r1w1 = (const float*)d_in[12];
    const float* r1b1 = (const float*)d_in[13];
    const float* r1w2 = (const float*)d_in[14];
    const float* r1b2 = (const float*)d_in[15];
    const float* r2w1 = (const float*)d_in[16];
    const float* r2b1 = (const float*)d_in[17];
    const float* r2w2 = (const float*)d_in[18];
    const float* r2b2 = (const float*)d_in[19];

    float* agg = (float*)d_ws;            // NODES*72
    float* hA  = agg + (size_t)NODES * 72;
    float* hB  = hA  + (size_t)NODES * 72;
    float* hb  = hB  + (size_t)NODES * 72; // EDGES*72

    const size_t aggBytes = (size_t)NODES * 72 * sizeof(float);
    const int EB = EDGES / 32;       // 20000 blocks
    const int NBK = NODES * 8 / 256; // 1250 blocks

    // Layer 0
    hipMemsetAsync(agg, 0, aggBytes, stream);
    layer0_edge<<<EB, 256, 0, stream>>>(eidx, ev, x, embw, r0w1, r0b1, r0w2, r0b2, agg, hb);
    node0<<<NBK, 256, 0, stream>>>(x, embw, lin0, agg, hA);

    // Layer 1
    hipMemsetAsync(agg, 0, aggBytes, stream);
    tp_edge<<<EB, 256, 0, stream>>>(eidx, ev, hA, r1w1, r1b1, r1w2, r1b2, hb, agg);
    node12<<<NBK, 256, 0, stream>>>(hA, lin1, agg, hB);

    // Layer 2
    hipMemsetAsync(agg, 0, aggBytes, stream);
    tp_edge<<<EB, 256, 0, stream>>>(eidx, ev, hB, r2w1, r2b1, r2w2, r2b2, hb, agg);
    node12<<<NBK, 256, 0, stream>>>(hB, lin2, agg, hA);

    // Output head
    out_kernel<<<NBK, 256, 0, stream>>>(hA, outw, (float*)d_out);
}